// Round 1
// baseline (202.378 us; speedup 1.0000x reference)
//
#include <hip/hip_runtime.h>
#include <math.h>

#define NUM_GRID 16
#define NCELLS   256          // 16*16 cells per map
#define THRESH   0.65f
#define NUM_FG   40
#define NUM_BG   1
#define MAX_PTS  42
#define T_DIM    8
#define C_DIM    4
#define H_DIM    1024
#define W_DIM    1024
#define NMAPS    (T_DIM * C_DIM)          // 32
#define MAP_ELEMS (H_DIM * W_DIM)         // 1048576
#define CELL_DIM 64                       // 1024/16

// (value, index) block reduction over 256 threads.
// is_max: prefer larger value; else prefer smaller value. Ties -> smaller index.
__device__ inline void block_reduce_pair(float& v, int& i, bool is_max,
                                         float* sv, int* si, int tid) {
    sv[tid] = v; si[tid] = i;
    __syncthreads();
    for (int s = 128; s > 0; s >>= 1) {
        if (tid < s) {
            float v2 = sv[tid + s]; int i2 = si[tid + s];
            float v1 = sv[tid];     int i1 = si[tid];
            bool take = is_max ? (v2 > v1 || (v2 == v1 && i2 < i1))
                               : (v2 < v1 || (v2 == v1 && i2 < i1));
            if (take) { sv[tid] = v2; si[tid] = i2; }
        }
        __syncthreads();
    }
    v = sv[0]; i = si[0];
    __syncthreads();   // safe reuse of sv/si afterwards
}

// Kernel 1: one block per (map, cell). 256 threads, 16 px/thread via float4.
// Produces per-cell: fg-masked max (+min flat idx among ties),
//                    unmasked max (+min idx), unmasked min (+min idx).
__global__ __launch_bounds__(256)
void cell_stats_kernel(const float* __restrict__ sim,
                       float* __restrict__ fgmax_o, int* __restrict__ fgarg_o,
                       float* __restrict__ amax_o,  int* __restrict__ amaxarg_o,
                       float* __restrict__ amin_o,  int* __restrict__ aminarg_o) {
    const int b    = blockIdx.x;       // 0..NMAPS*NCELLS-1
    const int map  = b >> 8;
    const int cell = b & 255;
    const int cy   = cell >> 4;
    const int cx   = cell & 15;
    const int tid  = threadIdx.x;
    const int g    = tid & 15;         // col group (4 floats each)
    const int rr   = tid >> 4;         // row offset 0..15

    const float* base = sim + (size_t)map * MAP_ELEMS;

    float fgv = -INFINITY; int fgi = 0x7fffffff;
    float mxv = -INFINITY; int mxi = 0x7fffffff;
    float mnv =  INFINITY; int mni = 0x7fffffff;

    #pragma unroll
    for (int r = 0; r < 4; ++r) {
        const int row = cy * CELL_DIM + r * 16 + rr;   // increasing with r
        const int col = cx * CELL_DIM + g * 4;
        const int idx = row * W_DIM + col;
        const float4 v4 = *reinterpret_cast<const float4*>(base + idx);
        const float vals[4] = {v4.x, v4.y, v4.z, v4.w};
        #pragma unroll
        for (int j = 0; j < 4; ++j) {
            const float v  = vals[j];
            const int   ix = idx + j;
            // processed in increasing flat-index order -> strict compares keep min idx
            if (v > mxv) { mxv = v; mxi = ix; }
            if (v < mnv) { mnv = v; mni = ix; }
            if (v > THRESH && v > fgv) { fgv = v; fgi = ix; }
        }
    }

    __shared__ float sv[256];
    __shared__ int   si[256];

    block_reduce_pair(fgv, fgi, true,  sv, si, tid);
    block_reduce_pair(mxv, mxi, true,  sv, si, tid);
    block_reduce_pair(mnv, mni, false, sv, si, tid);

    if (tid == 0) {
        const int o = map * NCELLS + cell;
        fgmax_o[o]   = fgv;  fgarg_o[o]   = fgi;
        amax_o[o]    = mxv;  amaxarg_o[o] = mxi;
        amin_o[o]    = mnv;  aminarg_o[o] = mni;
    }
}

// Kernel 2: one block per map. 256 threads, one per cell.
// Stable descending rank of fg scores, top-40 rows, bg row, num.
__global__ __launch_bounds__(256)
void select_kernel(const float* __restrict__ fgmax_i, const int* __restrict__ fgarg_i,
                   const float* __restrict__ amax_i,  const int* __restrict__ amaxarg_i,
                   const float* __restrict__ amin_i,  const int* __restrict__ aminarg_i,
                   const int* __restrict__ orig_sizes,
                   float* __restrict__ out_pts, float* __restrict__ out_nums) {
    const int m   = blockIdx.x;    // 0..31
    const int tid = threadIdx.x;   // cell id
    const int t   = m >> 2;        // map = t*C + c

    const float sx = (float)orig_sizes[t * 2 + 1] / (float)W_DIM;
    const float sy = (float)orig_sizes[t * 2 + 0] / (float)H_DIM;

    const int o = m * NCELLS + tid;
    const float fgv = fgmax_i[o];          // -inf if cell has no fg pixel
    const int   fgi = fgarg_i[o];
    const bool  valid = (fgv > -INFINITY); // isfinite(cell_max)

    __shared__ float skey[256];
    skey[tid] = fgv;                        // key = valid ? score : -inf (== fgv)

    __shared__ float sv[256];
    __shared__ int   si[256];

    // global (unmasked) max with min-idx tie-break  -> jnp.argmax fallback
    float gv = amax_i[o]; int gi = amaxarg_i[o];
    block_reduce_pair(gv, gi, true, sv, si, tid);
    // global min with min-idx tie-break             -> top_k(-flat, 1)
    float bv = amin_i[o]; int bi = aminarg_i[o];
    block_reduce_pair(bv, bi, false, sv, si, tid);

    const int nvalid = __syncthreads_count(valid ? 1 : 0);
    const bool any_fg = (nvalid > 0);
    const int fg_count = any_fg ? (nvalid < NUM_FG ? nvalid : NUM_FG) : 1;

    // stable descending rank: #{j : key_j > key_i or (key_j == key_i and j < i)}
    int rank = 0;
    const float key = fgv;
    for (int j = 0; j < 256; ++j) {
        const float kj = skey[j];
        rank += (kj > key || (kj == key && j < tid)) ? 1 : 0;
    }

    __shared__ float outp[MAX_PTS * 4];
    if (tid < MAX_PTS * 4) outp[tid] = 0.0f;
    __syncthreads();

    if (any_fg && valid && rank < NUM_FG) {
        const int col = fgi & (W_DIM - 1);
        const int row = fgi >> 10;
        outp[rank * 4 + 0] = (float)col * sx;
        outp[rank * 4 + 1] = (float)row * sy;
        outp[rank * 4 + 2] = fgv;
        outp[rank * 4 + 3] = 1.0f;
    }
    if (!any_fg && tid == 0) {
        const int col = gi & (W_DIM - 1);
        const int row = gi >> 10;
        outp[0] = (float)col * sx;
        outp[1] = (float)row * sy;
        outp[2] = gv;
        outp[3] = 1.0f;
    }
    __syncthreads();

    if (tid == 0) {
        const int col = bi & (W_DIM - 1);
        const int row = bi >> 10;
        outp[fg_count * 4 + 0] = (float)col * sx;
        outp[fg_count * 4 + 1] = (float)row * sy;
        outp[fg_count * 4 + 2] = bv;
        outp[fg_count * 4 + 3] = 0.0f;
    }
    __syncthreads();

    if (tid < MAX_PTS * 4) out_pts[(size_t)m * (MAX_PTS * 4) + tid] = outp[tid];
    if (tid == 0) out_nums[m] = (float)(fg_count + NUM_BG);
}

extern "C" void kernel_launch(void* const* d_in, const int* in_sizes, int n_in,
                              void* d_out, int out_size, void* d_ws, size_t ws_size,
                              hipStream_t stream) {
    const float* sim        = (const float*)d_in[0];
    // d_in[1] = category_ids (unused by forward)
    const int*   orig_sizes = (const int*)d_in[2];

    float* out = (float*)d_out;
    float* out_pts  = out;                                   // (T,C,42,4) = 5376 floats
    float* out_nums = out + (size_t)NMAPS * MAX_PTS * 4;     // (T,C)      = 32 floats

    // workspace layout: 8192 cells, SoA
    const size_t NC = (size_t)NMAPS * NCELLS;                // 8192
    char* ws = (char*)d_ws;
    float* fgmax_ws   = (float*)(ws + 0 * NC * 4);
    int*   fgarg_ws   = (int*)  (ws + 1 * NC * 4);
    float* amax_ws    = (float*)(ws + 2 * NC * 4);
    int*   amaxarg_ws = (int*)  (ws + 3 * NC * 4);
    float* amin_ws    = (float*)(ws + 4 * NC * 4);
    int*   aminarg_ws = (int*)  (ws + 5 * NC * 4);

    cell_stats_kernel<<<NMAPS * NCELLS, 256, 0, stream>>>(
        sim, fgmax_ws, fgarg_ws, amax_ws, amaxarg_ws, amin_ws, aminarg_ws);

    select_kernel<<<NMAPS, 256, 0, stream>>>(
        fgmax_ws, fgarg_ws, amax_ws, amaxarg_ws, amin_ws, aminarg_ws,
        orig_sizes, out_pts, out_nums);
}